// Round 1
// baseline (1990.162 us; speedup 1.0000x reference)
//
#include <hip/hip_runtime.h>
#include <hip/hip_fp16.h>
#include <cfloat>
#include <cmath>

// GNN_Combo pipeline, fp32 correctness-first baseline.
// N=16384 nodes, F=64 in-features, H=128 hidden, K=16 neighbors, O=10 classes.
//
// Pipeline:
//  k_prep      : sq[i]=||x_i||^2 (fp32 + fp64)
//  k_dist      : fused distance + per-segment top-18 candidates (fp32), 8 segs/row
//  k_rescore   : fp64 exact rescoring of 144 candidates/row -> exact top-16 (knn)
//  k_lin1<P/Q> : factorized EdgeConv layer1: P = x@(W1top-W1bot)+b1, Q = x@W1bot
//  k_edgeconv  : per (i,j): relu(P_i+Q_j) @ W2 + b2 -> log_softmax -> max over j
//  k_hw        : hw = h @ gcn_w
//  k_heads     : h_gcn = (sum_{17} hw)/17 + gcn_b; softmax(h@Wgo+b); softmax(h@Wo+b)
//
// Workspace (~34.2 MB): sq | sq64 | cand | knn | P | Q | h   (hw aliases P)

#define N_NODES 16384
#define F_IN    64
#define H_DIM   128
#define K_NN    16
#define O_DIM   10
#define J_SEG   18
#define SEGS    8
#define CAND    (J_SEG*SEGS)   // 144

// ---------------------------------------------------------------- k_prep ----
__global__ __launch_bounds__(256) void k_prep(const float* __restrict__ x,
                                              float* __restrict__ sq,
                                              double* __restrict__ sq64) {
  const int i = blockIdx.x * 256 + threadIdx.x;
  if (i >= N_NODES) return;
  const float4* r = (const float4*)(x + i * F_IN);
  float s = 0.f; double sd = 0.0;
#pragma unroll
  for (int q = 0; q < 16; ++q) {
    const float4 v = r[q];
    s += v.x*v.x + v.y*v.y + v.z*v.z + v.w*v.w;
    sd += (double)v.x*v.x + (double)v.y*v.y + (double)v.z*v.z + (double)v.w*v.w;
  }
  sq[i] = s; sq64[i] = sd;
}

// ---------------------------------------------------------------- k_dist ----
// 512 threads: 64 query rows/block x 8 column-segments. Each thread holds its
// query row (64 VGPRs) and a private top-J_SEG list; column tiles of 128 are
// staged in LDS and read via broadcast float4 loads.
__global__ __launch_bounds__(512) void k_dist(const float* __restrict__ x,
                                              const float* __restrict__ sq,
                                              int* __restrict__ cand) {
  __shared__ float xt[128][F_IN];   // 32 KB
  __shared__ float sqt[128];
  const int t  = threadIdx.x;
  const int qr = t & 63;
  const int seg = t >> 6;           // 0..7
  const int qi = blockIdx.x * 64 + qr;
  float xi[F_IN];
  {
    const float4* r = (const float4*)(x + qi * F_IN);
#pragma unroll
    for (int q = 0; q < 16; ++q) {
      const float4 v = r[q];
      xi[4*q] = v.x; xi[4*q+1] = v.y; xi[4*q+2] = v.z; xi[4*q+3] = v.w;
    }
  }
  float cd[J_SEG]; int ci[J_SEG];
#pragma unroll
  for (int s = 0; s < J_SEG; ++s) { cd[s] = FLT_MAX; ci[s] = 0; }
  float worst = FLT_MAX; int wslot = 0;

  for (int c0 = 0; c0 < N_NODES; c0 += 128) {
    __syncthreads();
    {
      const int row = t >> 4, f4 = (t & 15) * 4;
#pragma unroll
      for (int p = 0; p < 4; ++p)
        *(float4*)&xt[row + 32*p][f4] = *(const float4*)&x[(c0 + row + 32*p)*F_IN + f4];
      if (t < 128) sqt[t] = sq[c0 + t];
    }
    __syncthreads();
#pragma unroll 1
    for (int kk = 0; kk < 16; ++kk) {
      const int cc = seg * 16 + kk;    // wave-uniform -> broadcast LDS reads
      float a0 = 0.f, a1 = 0.f, a2 = 0.f, a3 = 0.f;
#pragma unroll
      for (int q = 0; q < 16; ++q) {
        const float4 b = *(const float4*)&xt[cc][4*q];
        a0 = fmaf(xi[4*q+0], b.x, a0);
        a1 = fmaf(xi[4*q+1], b.y, a1);
        a2 = fmaf(xi[4*q+2], b.z, a2);
        a3 = fmaf(xi[4*q+3], b.w, a3);
      }
      const float key = sqt[cc] - 2.0f * ((a0 + a1) + (a2 + a3)); // sq_i shift is rank-invariant
      if (key < worst) {
        const int id = c0 + cc;
#pragma unroll
        for (int s = 0; s < J_SEG; ++s) if (s == wslot) { cd[s] = key; ci[s] = id; }
        float w = -FLT_MAX; int wp2 = 0;
#pragma unroll
        for (int s = 0; s < J_SEG; ++s) if (cd[s] > w) { w = cd[s]; wp2 = s; }
        worst = w; wslot = wp2;
      }
    }
  }
  int* cp = cand + qi * CAND + seg * J_SEG;
#pragma unroll
  for (int s = 0; s < J_SEG; ++s) cp[s] = ci[s];
}

// ------------------------------------------------------------- k_rescore ----
// One block per node; 144 candidates rescored in fp64, exact rank-select of
// top-16 with (key, id) lexicographic tie-break (matches stable jax.lax.top_k).
__global__ __launch_bounds__(192) void k_rescore(const float* __restrict__ x,
                                                 const double* __restrict__ sq64,
                                                 const int* __restrict__ cand,
                                                 int* __restrict__ knn) {
  __shared__ float  xi[F_IN];
  __shared__ double keys[192];
  __shared__ int    ids[192];
  const int i = blockIdx.x, t = threadIdx.x;
  if (t < F_IN) xi[t] = x[i * F_IN + t];
  __syncthreads();
  double key = 1e300; int id = 0x7fffffff;
  if (t < CAND) {
    id = cand[(size_t)i * CAND + t];
    const float4* xc4 = (const float4*)(x + (size_t)id * F_IN);
    double d0 = 0.0, d1 = 0.0, d2 = 0.0, d3 = 0.0;
#pragma unroll
    for (int q = 0; q < 16; ++q) {
      const float4 v = xc4[q];
      d0 += (double)xi[4*q+0] * (double)v.x;
      d1 += (double)xi[4*q+1] * (double)v.y;
      d2 += (double)xi[4*q+2] * (double)v.z;
      d3 += (double)xi[4*q+3] * (double)v.w;
    }
    key = sq64[id] - 2.0 * ((d0 + d1) + (d2 + d3));
  }
  keys[t] = key; ids[t] = id;
  __syncthreads();
  int rank = 0;
  for (int c = 0; c < CAND; ++c) {
    const double kc = keys[c]; const int ic = ids[c];
    rank += (kc < key) || (kc == key && ic < id);
  }
  if (t < CAND && rank < K_NN) knn[i * K_NN + rank] = id;
}

// --------------------------------------------------------------- k_lin1 -----
// Factorized EdgeConv layer1. PMODE: P = x@(W1top - W1bot) + b1; else Q = x@W1bot.
template <bool PMODE>
__global__ __launch_bounds__(256) void k_lin1(const float* __restrict__ x,
                                              const float* __restrict__ w1,
                                              const float* __restrict__ b1,
                                              float* __restrict__ dst) {
  __shared__ float wl[2 * F_IN][H_DIM];   // 64 KB
  for (int s = threadIdx.x; s < 2 * F_IN * H_DIM; s += 256) wl[s >> 7][s & 127] = w1[s];
  __syncthreads();
  const int node = blockIdx.x * 32 + (threadIdx.x & 31);
  const int ob = (threadIdx.x >> 5) * 16;   // 8 groups x 16 outs
  float acc[16];
#pragma unroll
  for (int o = 0; o < 16; ++o) acc[o] = 0.f;
  const float4* xr = (const float4*)(x + node * F_IN);
#define L1STEP(ff, xs) { \
    const float* wb = &wl[(ff) + F_IN][ob]; \
    const float* wt = &wl[(ff)][ob]; \
    _Pragma("unroll") \
    for (int o = 0; o < 16; o += 4) { \
      const float4 b4 = *(const float4*)(wb + o); \
      float wx, wy, wz, ww; \
      if (PMODE) { const float4 t4 = *(const float4*)(wt + o); \
        wx = t4.x - b4.x; wy = t4.y - b4.y; wz = t4.z - b4.z; ww = t4.w - b4.w; } \
      else { wx = b4.x; wy = b4.y; wz = b4.z; ww = b4.w; } \
      acc[o+0] = fmaf((xs), wx, acc[o+0]); \
      acc[o+1] = fmaf((xs), wy, acc[o+1]); \
      acc[o+2] = fmaf((xs), wz, acc[o+2]); \
      acc[o+3] = fmaf((xs), ww, acc[o+3]); } }
#pragma unroll 2
  for (int q = 0; q < 16; ++q) {
    const float4 xv = xr[q];
    L1STEP(4*q+0, xv.x); L1STEP(4*q+1, xv.y); L1STEP(4*q+2, xv.z); L1STEP(4*q+3, xv.w);
  }
#undef L1STEP
  float* dp = dst + node * H_DIM + ob;
#pragma unroll
  for (int o = 0; o < 16; ++o) dp[o] = PMODE ? (acc[o] + b1[ob + o]) : acc[o];
}

// ------------------------------------------------------------ k_edgeconv ----
// Wave-per-node. a1[m][f] = relu(P_i[f] + Q_{j_m}[f]); lane l holds channels
// {l, l+64} of all 16 messages. Layer2 via __shfl broadcast of a1 + W2 pairs
// from LDS; then in-register log_softmax (shfl reductions) and max over m.
__global__ __launch_bounds__(256) void k_edgeconv(const float* __restrict__ P,
                                                  const float* __restrict__ Q,
                                                  const float* __restrict__ w2,
                                                  const float* __restrict__ b2,
                                                  const int* __restrict__ knn,
                                                  float* __restrict__ h) {
  __shared__ float2 wp[H_DIM][64];   // 64 KB: (w2[f][l], w2[f][l+64])
  for (int s = threadIdx.x; s < H_DIM * 64; s += 256) {
    const int f = s >> 6, l = s & 63;
    wp[f][l] = make_float2(w2[f * H_DIM + l], w2[f * H_DIM + 64 + l]);
  }
  __syncthreads();
  const int wv = threadIdx.x >> 6, l = threadIdx.x & 63;
  const float b2l = b2[l], b2h = b2[64 + l];
  for (int it = 0; it < 8; ++it) {
    const int i = blockIdx.x * 32 + wv * 8 + it;
    const int* kr = knn + i * K_NN;
    const float p0 = P[i * H_DIM + l], p1 = P[i * H_DIM + 64 + l];
    float a0[K_NN], a1[K_NN];
#pragma unroll
    for (int m = 0; m < K_NN; ++m) {
      const int j = kr[m];
      a0[m] = fmaxf(p0 + Q[j * H_DIM + l], 0.f);
      a1[m] = fmaxf(p1 + Q[j * H_DIM + 64 + l], 0.f);
    }
    float z0[K_NN], z1[K_NN];
#pragma unroll
    for (int m = 0; m < K_NN; ++m) { z0[m] = b2l; z1[m] = b2h; }
#pragma unroll 2
    for (int f = 0; f < 64; ++f) {
      const float2 w = wp[f][l];
#pragma unroll
      for (int m = 0; m < K_NN; ++m) {
        const float av = __shfl(a0[m], f, 64);
        z0[m] = fmaf(av, w.x, z0[m]);
        z1[m] = fmaf(av, w.y, z1[m]);
      }
    }
#pragma unroll 2
    for (int f = 0; f < 64; ++f) {
      const float2 w = wp[64 + f][l];
#pragma unroll
      for (int m = 0; m < K_NN; ++m) {
        const float av = __shfl(a1[m], f, 64);
        z0[m] = fmaf(av, w.x, z0[m]);
        z1[m] = fmaf(av, w.y, z1[m]);
      }
    }
    float hm0 = -FLT_MAX, hm1 = -FLT_MAX;
#pragma unroll 1
    for (int m = 0; m < K_NN; ++m) {
      float mx = fmaxf(z0[m], z1[m]);
#pragma unroll
      for (int s = 1; s < 64; s <<= 1) mx = fmaxf(mx, __shfl_xor(mx, s, 64));
      float e = __expf(z0[m] - mx) + __expf(z1[m] - mx);
#pragma unroll
      for (int s = 1; s < 64; s <<= 1) e += __shfl_xor(e, s, 64);
      const float lse = mx + __logf(e);
      hm0 = fmaxf(hm0, z0[m] - lse);
      hm1 = fmaxf(hm1, z1[m] - lse);
    }
    h[i * H_DIM + l] = hm0;
    h[i * H_DIM + 64 + l] = hm1;
  }
}

// ----------------------------------------------------------------- k_hw -----
__global__ __launch_bounds__(256) void k_hw(const float* __restrict__ h,
                                            const float* __restrict__ gw,
                                            float* __restrict__ hw) {
  __shared__ float wl[H_DIM][H_DIM];   // 64 KB
  for (int s = threadIdx.x; s < H_DIM * H_DIM; s += 256) wl[s >> 7][s & 127] = gw[s];
  __syncthreads();
  const int node = blockIdx.x * 32 + (threadIdx.x & 31);
  const int ob = (threadIdx.x >> 5) * 16;
  float acc[16];
#pragma unroll
  for (int o = 0; o < 16; ++o) acc[o] = 0.f;
  const float4* hr = (const float4*)(h + node * H_DIM);
#define HWSTEP(ff, xs) { \
    const float* wr = &wl[(ff)][ob]; \
    _Pragma("unroll") \
    for (int o = 0; o < 16; o += 4) { const float4 w4 = *(const float4*)(wr + o); \
      acc[o+0] = fmaf((xs), w4.x, acc[o+0]); \
      acc[o+1] = fmaf((xs), w4.y, acc[o+1]); \
      acc[o+2] = fmaf((xs), w4.z, acc[o+2]); \
      acc[o+3] = fmaf((xs), w4.w, acc[o+3]); } }
#pragma unroll 2
  for (int q = 0; q < 32; ++q) {
    const float4 hv = hr[q];
    HWSTEP(4*q+0, hv.x); HWSTEP(4*q+1, hv.y); HWSTEP(4*q+2, hv.z); HWSTEP(4*q+3, hv.w);
  }
#undef HWSTEP
  float* dp = hw + node * H_DIM + ob;
#pragma unroll
  for (int o = 0; o < 16; ++o) dp[o] = acc[o];
}

// --------------------------------------------------------------- k_heads ----
// Wave-per-node: GCN gather/avg (+gcn_b), softmax(h@Wgo+b) over 128,
// softmax(h2@Wo+b) over 10. Wgo packed f16x2 in LDS (fits 64 KB budget;
// err contribution ~6e-4 << 2.2e-3 threshold).
__global__ __launch_bounds__(256) void k_heads(const float* __restrict__ hw,
                                               const int* __restrict__ knn,
                                               const float* __restrict__ gb,
                                               const float* __restrict__ gow,
                                               const float* __restrict__ gob,
                                               const float* __restrict__ ow,
                                               const float* __restrict__ obv,
                                               float* __restrict__ out) {
  __shared__ unsigned int wgo[H_DIM][64];  // 32 KB
  __shared__ float hbuf[4][H_DIM];         // 2 KB
  for (int s = threadIdx.x; s < H_DIM * 64; s += 256) {
    const int f = s >> 6, l = s & 63;
    const unsigned short u0 = __half_as_ushort(__float2half(gow[f * H_DIM + l]));
    const unsigned short u1 = __half_as_ushort(__float2half(gow[f * H_DIM + 64 + l]));
    wgo[f][l] = (unsigned int)u0 | ((unsigned int)u1 << 16);
  }
  __syncthreads();
  const int wv = threadIdx.x >> 6, l = threadIdx.x & 63;
  const float gbl = gb[l], gbh = gb[64 + l];
  const float gobl = gob[l], gobh = gob[64 + l];
  for (int it = 0; it < 8; ++it) {
    const int i = blockIdx.x * 32 + wv * 8 + it;
    const int* kr = knn + i * K_NN;
    float s0 = hw[i * H_DIM + l], s1 = hw[i * H_DIM + 64 + l];  // explicit self-loop
#pragma unroll
    for (int m = 0; m < K_NN; ++m) {
      const int j = kr[m];
      s0 += hw[j * H_DIM + l];
      s1 += hw[j * H_DIM + 64 + l];
    }
    // deg == k+1 == 17 for every node by construction -> norm == 1/17
    const float hg0 = s0 * (1.0f / 17.0f) + gbl;
    const float hg1 = s1 * (1.0f / 17.0f) + gbh;
    __syncthreads();
    hbuf[wv][l] = hg0; hbuf[wv][64 + l] = hg1;
    __syncthreads();
    float z0 = gobl, z1 = gobh;
#pragma unroll 4
    for (int f = 0; f < H_DIM; ++f) {
      const float hv = hbuf[wv][f];
      const unsigned int wvv = wgo[f][l];
      const float w0 = __half2float(__ushort_as_half((unsigned short)(wvv & 0xffffu)));
      const float w1 = __half2float(__ushort_as_half((unsigned short)(wvv >> 16)));
      z0 = fmaf(hv, w0, z0);
      z1 = fmaf(hv, w1, z1);
    }
    float mx = fmaxf(z0, z1);
#pragma unroll
    for (int s = 1; s < 64; s <<= 1) mx = fmaxf(mx, __shfl_xor(mx, s, 64));
    const float e0 = __expf(z0 - mx), e1 = __expf(z1 - mx);
    float sm = e0 + e1;
#pragma unroll
    for (int s = 1; s < 64; s <<= 1) sm += __shfl_xor(sm, s, 64);
    const float h20 = e0 / sm, h21 = e1 / sm;
    float zc[O_DIM];
#pragma unroll
    for (int c = 0; c < O_DIM; ++c) {
      float a = h20 * ow[l * O_DIM + c] + h21 * ow[(64 + l) * O_DIM + c];
#pragma unroll
      for (int s = 1; s < 64; s <<= 1) a += __shfl_xor(a, s, 64);
      zc[c] = a + obv[c];
    }
    float m10 = zc[0];
#pragma unroll
    for (int c = 1; c < O_DIM; ++c) m10 = fmaxf(m10, zc[c]);
    float es[O_DIM]; float s10 = 0.f;
#pragma unroll
    for (int c = 0; c < O_DIM; ++c) { es[c] = __expf(zc[c] - m10); s10 += es[c]; }
    const float inv = 1.0f / s10;
    if (l < O_DIM) {
      float v = es[0];
#pragma unroll
      for (int c = 1; c < O_DIM; ++c) if (l == c) v = es[c];
      out[i * O_DIM + l] = v * inv;
    }
  }
}

// ---------------------------------------------------------------------------
extern "C" void kernel_launch(void* const* d_in, const int* in_sizes, int n_in,
                              void* d_out, int out_size, void* d_ws, size_t ws_size,
                              hipStream_t stream) {
  (void)in_sizes; (void)n_in; (void)out_size; (void)ws_size;
  const float* x   = (const float*)d_in[0];
  // d_in[1] = edge_index (unused by forward)
  const float* w1  = (const float*)d_in[2];
  const float* b1  = (const float*)d_in[3];
  const float* w2  = (const float*)d_in[4];
  const float* b2  = (const float*)d_in[5];
  const float* gw  = (const float*)d_in[6];
  const float* gb  = (const float*)d_in[7];
  const float* gow = (const float*)d_in[8];
  const float* gob = (const float*)d_in[9];
  const float* ow  = (const float*)d_in[10];
  const float* obv = (const float*)d_in[11];
  // d_in[12] = k (always 16 for this problem)
  float* out = (float*)d_out;

  char* ws = (char*)d_ws;
  constexpr size_t OFF_SQ   = 0;
  constexpr size_t OFF_SQ64 = OFF_SQ   + (size_t)N_NODES * 4;            //  64 KB
  constexpr size_t OFF_CAND = OFF_SQ64 + (size_t)N_NODES * 8;            // 192 KB
  constexpr size_t OFF_KNN  = OFF_CAND + (size_t)N_NODES * CAND * 4;     // +9 MB
  constexpr size_t OFF_P    = OFF_KNN  + (size_t)N_NODES * K_NN * 4;     // +1 MB
  constexpr size_t OFF_Q    = OFF_P    + (size_t)N_NODES * H_DIM * 4;    // +8 MB
  constexpr size_t OFF_H    = OFF_Q    + (size_t)N_NODES * H_DIM * 4;    // +8 MB
  float*  sq   = (float*) (ws + OFF_SQ);
  double* sq64 = (double*)(ws + OFF_SQ64);
  int*    cand = (int*)   (ws + OFF_CAND);
  int*    knn  = (int*)   (ws + OFF_KNN);
  float*  P    = (float*) (ws + OFF_P);
  float*  Q    = (float*) (ws + OFF_Q);
  float*  h    = (float*) (ws + OFF_H);
  float*  hw   = (float*) (ws + OFF_P);   // hw aliases P (P dead after k_edgeconv)

  k_prep    <<<N_NODES / 256, 256, 0, stream>>>(x, sq, sq64);
  k_dist    <<<N_NODES / 64,  512, 0, stream>>>(x, sq, cand);
  k_rescore <<<N_NODES,       192, 0, stream>>>(x, sq64, cand, knn);
  k_lin1<true>  <<<N_NODES / 32, 256, 0, stream>>>(x, w1, b1, P);
  k_lin1<false> <<<N_NODES / 32, 256, 0, stream>>>(x, w1, b1, Q);
  k_edgeconv<<<N_NODES / 32, 256, 0, stream>>>(P, Q, w2, b2, knn, h);
  k_hw      <<<N_NODES / 32, 256, 0, stream>>>(h, gw, hw);
  k_heads   <<<N_NODES / 32, 256, 0, stream>>>(hw, knn, gb, gow, gob, ow, obv, out);
}

// Round 2
// 982.698 us; speedup vs baseline: 2.0252x; 2.0252x over previous
//
#include <hip/hip_runtime.h>
#include <hip/hip_fp16.h>
#include <cfloat>
#include <cmath>

// GNN_Combo pipeline. Round 2: MFMA-based kNN distance path.
// N=16384 nodes, F=64 in-features, H=128 hidden, K=16 neighbors, O=10 classes.
//
// kNN path (new):
//  k_prep     : sq (fp32), sq64 (fp64), xhl = f16 hi/lo split of x (packed [hi64|lo64])
//  k_gemm<1>  : MFMA keys (3-term f16 split, ~1e-5 abs err) + per-(row,512-col-chunk)
//               running min -> cmins[N][32]  (no selection lists, no branches)
//  k_tau      : tau0[row] = 16th-smallest chunk-min (provably >= true 16th key);
//               zeroes cnt[]
//  k_gemm<2>  : identical GEMM; appends cols with key <= tau0 (E[cnt]~23, cap 128)
//  k_rescore  : fp64 exact rescoring of cnt candidates -> exact top-16 (knn)
// Rest unchanged from round 1.

#define N_NODES 16384
#define F_IN    64
#define H_DIM   128
#define K_NN    16
#define O_DIM   10

typedef _Float16 half8  __attribute__((ext_vector_type(8)));
typedef _Float16 half4v __attribute__((ext_vector_type(4)));
typedef float    floatx4 __attribute__((ext_vector_type(4)));

// ---------------------------------------------------------------- k_prep ----
__global__ __launch_bounds__(256) void k_prep(const float* __restrict__ x,
                                              float* __restrict__ sq,
                                              double* __restrict__ sq64,
                                              _Float16* __restrict__ xhl) {
  const int i = blockIdx.x * 256 + threadIdx.x;
  if (i >= N_NODES) return;
  const float4* r = (const float4*)(x + i * F_IN);
  float s = 0.f; double sd = 0.0;
#pragma unroll
  for (int q = 0; q < 16; ++q) {
    const float4 v = r[q];
    s += v.x*v.x + v.y*v.y + v.z*v.z + v.w*v.w;
    sd += (double)v.x*v.x + (double)v.y*v.y + (double)v.z*v.z + (double)v.w*v.w;
    half4v hi, lo;
    hi[0] = (_Float16)v.x; hi[1] = (_Float16)v.y;
    hi[2] = (_Float16)v.z; hi[3] = (_Float16)v.w;
    lo[0] = (_Float16)(v.x - (float)hi[0]); lo[1] = (_Float16)(v.y - (float)hi[1]);
    lo[2] = (_Float16)(v.z - (float)hi[2]); lo[3] = (_Float16)(v.w - (float)hi[3]);
    *(half4v*)(xhl + (size_t)i * 128 + 4 * q)      = hi;
    *(half4v*)(xhl + (size_t)i * 128 + 64 + 4 * q) = lo;
  }
  sq[i] = s; sq64[i] = sd;
}

// ---------------------------------------------------------------- k_gemm ----
// Grid: 64 rowblocks (256 rows) x 8 col-segments (2048 cols) = 512 blocks.
// Block: 256 thr / 4 waves; wave owns 64 rows (4 MFMA rowsets). Column tiles
// of 128 staged in LDS (f16, +8-half pad -> 2-way-max bank aliasing, free).
// Per 16-col subtile: 4 B-frags (ds_read_b128) serve 24 mfma (4 rowsets x 6
// K-blocks of the 3-term hi/lo split). key = sq[col] - 2*dot (row-shift is
// rank-invariant; identical instruction sequence both phases -> bit-identical).
template<int PHASE>
__global__ __launch_bounds__(256, 2) void k_gemm(const _Float16* __restrict__ xhl,
                                                 const float* __restrict__ sq,
                                                 const float* __restrict__ tau,
                                                 float* __restrict__ cmins,
                                                 unsigned* __restrict__ cnt,
                                                 int* __restrict__ cand) {
  __shared__ __align__(16) _Float16 stage[128 * 136];  // 34816 B
  __shared__ float sqs[128];
  const int tid = threadIdx.x;
  const int wv = tid >> 6, l = tid & 63;
  const int lane16 = l & 15, quad = l >> 4;
  const int rowblk = (blockIdx.x >> 3) * 256;
  const int seg = blockIdx.x & 7;
  const int rw = rowblk + wv * 64;

  half8 A[4][4];  // [rowset][kb: hi0,hi1,lo0,lo1]
#pragma unroll
  for (int s = 0; s < 4; ++s) {
    const _Float16* ap = xhl + (size_t)(rw + s * 16 + lane16) * 128 + quad * 8;
#pragma unroll
    for (int kb = 0; kb < 4; ++kb) A[s][kb] = *(const half8*)(ap + kb * 32);
  }
  float tau_r[16];
  float rmin[16];
  if (PHASE == 2) {
#pragma unroll
    for (int s = 0; s < 4; ++s)
#pragma unroll
      for (int q = 0; q < 4; ++q)
        tau_r[s * 4 + q] = tau[rw + s * 16 + quad * 4 + q];
  } else {
#pragma unroll
    for (int t = 0; t < 16; ++t) rmin[t] = FLT_MAX;
  }

  for (int tile = 0; tile < 16; ++tile) {
    const int c0 = seg * 2048 + tile * 128;
    __syncthreads();
    {
      const int col = tid >> 1, part = tid & 1;
      const _Float16* g = xhl + (size_t)(c0 + col) * 128 + part * 64;
      _Float16* d = stage + col * 136 + part * 64;
#pragma unroll
      for (int j = 0; j < 8; ++j)
        *(half8*)(d + j * 8) = *(const half8*)(g + j * 8);
      if (tid < 128) sqs[tid] = sq[c0 + tid];
    }
    __syncthreads();
#pragma unroll 1
    for (int st = 0; st < 8; ++st) {
      const _Float16* bp = stage + (st * 16 + lane16) * 136 + quad * 8;
      const half8 B0 = *(const half8*)(bp);        // hi feats 0-31
      const half8 B1 = *(const half8*)(bp + 32);   // hi feats 32-63
      const half8 B2 = *(const half8*)(bp + 64);   // lo feats 0-31
      const half8 B3 = *(const half8*)(bp + 96);   // lo feats 32-63
      const float sqv = sqs[st * 16 + lane16];
      floatx4 acc[4];
#pragma unroll
      for (int s = 0; s < 4; ++s) acc[s] = (floatx4)0.f;
#define MF(s, ab, bb) acc[s] = __builtin_amdgcn_mfma_f32_16x16x32_f16(A[s][ab], bb, acc[s], 0, 0, 0)
#pragma unroll
      for (int s = 0; s < 4; ++s) MF(s, 0, B0);   // hi*hi
#pragma unroll
      for (int s = 0; s < 4; ++s) MF(s, 1, B1);
#pragma unroll
      for (int s = 0; s < 4; ++s) MF(s, 2, B0);   // lo*hi
#pragma unroll
      for (int s = 0; s < 4; ++s) MF(s, 3, B1);
#pragma unroll
      for (int s = 0; s < 4; ++s) MF(s, 0, B2);   // hi*lo
#pragma unroll
      for (int s = 0; s < 4; ++s) MF(s, 1, B3);
#undef MF
      if (PHASE == 1) {
#pragma unroll
        for (int s = 0; s < 4; ++s)
#pragma unroll
          for (int q = 0; q < 4; ++q)
            rmin[s * 4 + q] = fminf(rmin[s * 4 + q], fmaf(-2.f, acc[s][q], sqv));
      } else {
        const int colb = c0 + st * 16 + lane16;
#pragma unroll
        for (int s = 0; s < 4; ++s) {
          const float k0 = fmaf(-2.f, acc[s][0], sqv);
          const float k1 = fmaf(-2.f, acc[s][1], sqv);
          const float k2 = fmaf(-2.f, acc[s][2], sqv);
          const float k3 = fmaf(-2.f, acc[s][3], sqv);
          const float d01 = fminf(k0 - tau_r[s * 4 + 0], k1 - tau_r[s * 4 + 1]);
          const float d23 = fminf(k2 - tau_r[s * 4 + 2], k3 - tau_r[s * 4 + 3]);
          if (__ballot(fminf(d01, d23) <= 0.f)) {
            const int rbase = rw + s * 16 + quad * 4;
            if (k0 <= tau_r[s * 4 + 0]) {
              const unsigned pos = atomicAdd(&cnt[rbase + 0], 1u);
              if (pos < 128u) cand[(size_t)(rbase + 0) * 128 + pos] = colb;
            }
            if (k1 <= tau_r[s * 4 + 1]) {
              const unsigned pos = atomicAdd(&cnt[rbase + 1], 1u);
              if (pos < 128u) cand[(size_t)(rbase + 1) * 128 + pos] = colb;
            }
            if (k2 <= tau_r[s * 4 + 2]) {
              const unsigned pos = atomicAdd(&cnt[rbase + 2], 1u);
              if (pos < 128u) cand[(size_t)(rbase + 2) * 128 + pos] = colb;
            }
            if (k3 <= tau_r[s * 4 + 3]) {
              const unsigned pos = atomicAdd(&cnt[rbase + 3], 1u);
              if (pos < 128u) cand[(size_t)(rbase + 3) * 128 + pos] = colb;
            }
          }
        }
      }
    }
    if (PHASE == 1 && (tile & 3) == 3) {   // chunk boundary (512 cols)
#pragma unroll
      for (int t = 0; t < 16; ++t) {
#pragma unroll
        for (int d = 1; d < 16; d <<= 1)
          rmin[t] = fminf(rmin[t], __shfl_xor(rmin[t], d, 64));
      }
      const int chunk = seg * 4 + (tile >> 2);
      float v = rmin[0];
#pragma unroll
      for (int t = 1; t < 16; ++t) if (lane16 == t) v = rmin[t];
      const int row = rw + (lane16 >> 2) * 16 + quad * 4 + (lane16 & 3);
      cmins[(size_t)row * 32 + chunk] = v;
#pragma unroll
      for (int t = 0; t < 16; ++t) rmin[t] = FLT_MAX;
    }
  }
}

// ----------------------------------------------------------------- k_tau ----
// tau0[row] = 16th-smallest of the 32 chunk-mins (valid threshold: the 16
// smallest chunk-mins are 16 distinct keys <= tau0). Also zeroes cnt.
__global__ __launch_bounds__(256) void k_tau(const float* __restrict__ cmins,
                                             float* __restrict__ tau,
                                             unsigned* __restrict__ cnt) {
  const int r = blockIdx.x * 256 + threadIdx.x;
  if (r >= N_NODES) return;
  float v[32];
#pragma unroll
  for (int j = 0; j < 32; ++j) v[j] = cmins[(size_t)r * 32 + j];
  float t16 = FLT_MAX;
#pragma unroll 1
  for (int j = 0; j < 32; ++j) {
    int rk = 0;
#pragma unroll
    for (int m = 0; m < 32; ++m)
      rk += (v[m] < v[j]) || (v[m] == v[j] && m < j);
    if (rk == 15) t16 = v[j];
  }
  tau[r] = t16;
  cnt[r] = 0;
}

// ------------------------------------------------------------- k_rescore ----
// fp64 exact rescoring of the <=128 collected candidates; rank-select top-16
// with (key, id) lexicographic tie-break (matches stable jax.lax.top_k).
__global__ __launch_bounds__(128) void k_rescore(const float* __restrict__ x,
                                                 const double* __restrict__ sq64,
                                                 const int* __restrict__ cand,
                                                 const unsigned* __restrict__ cnt,
                                                 int* __restrict__ knn) {
  __shared__ float  xi[F_IN];
  __shared__ double keys[128];
  __shared__ int    ids[128];
  const int i = blockIdx.x, t = threadIdx.x;
  const unsigned c = cnt[i];
  const int n = (int)(c < 128u ? c : 128u);
  if (t < F_IN) xi[t] = x[i * F_IN + t];
  __syncthreads();
  double key = 1e300; int id = 0x7fffffff;
  if (t < n) {
    id = cand[(size_t)i * 128 + t];
    const float4* xc4 = (const float4*)(x + (size_t)id * F_IN);
    double d0 = 0.0, d1 = 0.0, d2 = 0.0, d3 = 0.0;
#pragma unroll
    for (int q = 0; q < 16; ++q) {
      const float4 v = xc4[q];
      d0 += (double)xi[4*q+0] * (double)v.x;
      d1 += (double)xi[4*q+1] * (double)v.y;
      d2 += (double)xi[4*q+2] * (double)v.z;
      d3 += (double)xi[4*q+3] * (double)v.w;
    }
    key = sq64[id] - 2.0 * ((d0 + d1) + (d2 + d3));
  }
  keys[t] = key; ids[t] = id;
  __syncthreads();
  int rank = 0;
#pragma unroll 4
  for (int cix = 0; cix < 128; ++cix) {
    const double kc = keys[cix]; const int ic = ids[cix];
    rank += (kc < key) || (kc == key && ic < id);
  }
  if (t < n && rank < K_NN) knn[i * K_NN + rank] = id;
}

// --------------------------------------------------------------- k_lin1 -----
// Factorized EdgeConv layer1. PMODE: P = x@(W1top - W1bot) + b1; else Q = x@W1bot.
template <bool PMODE>
__global__ __launch_bounds__(256) void k_lin1(const float* __restrict__ x,
                                              const float* __restrict__ w1,
                                              const float* __restrict__ b1,
                                              float* __restrict__ dst) {
  __shared__ float wl[2 * F_IN][H_DIM];   // 64 KB
  for (int s = threadIdx.x; s < 2 * F_IN * H_DIM; s += 256) wl[s >> 7][s & 127] = w1[s];
  __syncthreads();
  const int node = blockIdx.x * 32 + (threadIdx.x & 31);
  const int ob = (threadIdx.x >> 5) * 16;   // 8 groups x 16 outs
  float acc[16];
#pragma unroll
  for (int o = 0; o < 16; ++o) acc[o] = 0.f;
  const float4* xr = (const float4*)(x + node * F_IN);
#define L1STEP(ff, xs) { \
    const float* wb = &wl[(ff) + F_IN][ob]; \
    const float* wt = &wl[(ff)][ob]; \
    _Pragma("unroll") \
    for (int o = 0; o < 16; o += 4) { \
      const float4 b4 = *(const float4*)(wb + o); \
      float wx, wy, wz, ww; \
      if (PMODE) { const float4 t4 = *(const float4*)(wt + o); \
        wx = t4.x - b4.x; wy = t4.y - b4.y; wz = t4.z - b4.z; ww = t4.w - b4.w; } \
      else { wx = b4.x; wy = b4.y; wz = b4.z; ww = b4.w; } \
      acc[o+0] = fmaf((xs), wx, acc[o+0]); \
      acc[o+1] = fmaf((xs), wy, acc[o+1]); \
      acc[o+2] = fmaf((xs), wz, acc[o+2]); \
      acc[o+3] = fmaf((xs), ww, acc[o+3]); } }
#pragma unroll 2
  for (int q = 0; q < 16; ++q) {
    const float4 xv = xr[q];
    L1STEP(4*q+0, xv.x); L1STEP(4*q+1, xv.y); L1STEP(4*q+2, xv.z); L1STEP(4*q+3, xv.w);
  }
#undef L1STEP
  float* dp = dst + node * H_DIM + ob;
#pragma unroll
  for (int o = 0; o < 16; ++o) dp[o] = PMODE ? (acc[o] + b1[ob + o]) : acc[o];
}

// ------------------------------------------------------------ k_edgeconv ----
__global__ __launch_bounds__(256) void k_edgeconv(const float* __restrict__ P,
                                                  const float* __restrict__ Q,
                                                  const float* __restrict__ w2,
                                                  const float* __restrict__ b2,
                                                  const int* __restrict__ knn,
                                                  float* __restrict__ h) {
  __shared__ float2 wp[H_DIM][64];   // 64 KB: (w2[f][l], w2[f][l+64])
  for (int s = threadIdx.x; s < H_DIM * 64; s += 256) {
    const int f = s >> 6, l = s & 63;
    wp[f][l] = make_float2(w2[f * H_DIM + l], w2[f * H_DIM + 64 + l]);
  }
  __syncthreads();
  const int wv = threadIdx.x >> 6, l = threadIdx.x & 63;
  const float b2l = b2[l], b2h = b2[64 + l];
  for (int it = 0; it < 8; ++it) {
    const int i = blockIdx.x * 32 + wv * 8 + it;
    const int* kr = knn + i * K_NN;
    const float p0 = P[i * H_DIM + l], p1 = P[i * H_DIM + 64 + l];
    float a0[K_NN], a1[K_NN];
#pragma unroll
    for (int m = 0; m < K_NN; ++m) {
      const int j = kr[m];
      a0[m] = fmaxf(p0 + Q[j * H_DIM + l], 0.f);
      a1[m] = fmaxf(p1 + Q[j * H_DIM + 64 + l], 0.f);
    }
    float z0[K_NN], z1[K_NN];
#pragma unroll
    for (int m = 0; m < K_NN; ++m) { z0[m] = b2l; z1[m] = b2h; }
#pragma unroll 2
    for (int f = 0; f < 64; ++f) {
      const float2 w = wp[f][l];
#pragma unroll
      for (int m = 0; m < K_NN; ++m) {
        const float av = __shfl(a0[m], f, 64);
        z0[m] = fmaf(av, w.x, z0[m]);
        z1[m] = fmaf(av, w.y, z1[m]);
      }
    }
#pragma unroll 2
    for (int f = 0; f < 64; ++f) {
      const float2 w = wp[64 + f][l];
#pragma unroll
      for (int m = 0; m < K_NN; ++m) {
        const float av = __shfl(a1[m], f, 64);
        z0[m] = fmaf(av, w.x, z0[m]);
        z1[m] = fmaf(av, w.y, z1[m]);
      }
    }
    float hm0 = -FLT_MAX, hm1 = -FLT_MAX;
#pragma unroll 1
    for (int m = 0; m < K_NN; ++m) {
      float mx = fmaxf(z0[m], z1[m]);
#pragma unroll
      for (int s = 1; s < 64; s <<= 1) mx = fmaxf(mx, __shfl_xor(mx, s, 64));
      float e = __expf(z0[m] - mx) + __expf(z1[m] - mx);
#pragma unroll
      for (int s = 1; s < 64; s <<= 1) e += __shfl_xor(e, s, 64);
      const float lse = mx + __logf(e);
      hm0 = fmaxf(hm0, z0[m] - lse);
      hm1 = fmaxf(hm1, z1[m] - lse);
    }
    h[i * H_DIM + l] = hm0;
    h[i * H_DIM + 64 + l] = hm1;
  }
}

// ----------------------------------------------------------------- k_hw -----
__global__ __launch_bounds__(256) void k_hw(const float* __restrict__ h,
                                            const float* __restrict__ gw,
                                            float* __restrict__ hw) {
  __shared__ float wl[H_DIM][H_DIM];   // 64 KB
  for (int s = threadIdx.x; s < H_DIM * H_DIM; s += 256) wl[s >> 7][s & 127] = gw[s];
  __syncthreads();
  const int node = blockIdx.x * 32 + (threadIdx.x & 31);
  const int ob = (threadIdx.x >> 5) * 16;
  float acc[16];
#pragma unroll
  for (int o = 0; o < 16; ++o) acc[o] = 0.f;
  const float4* hr = (const float4*)(h + node * H_DIM);
#define HWSTEP(ff, xs) { \
    const float* wr = &wl[(ff)][ob]; \
    _Pragma("unroll") \
    for (int o = 0; o < 16; o += 4) { const float4 w4 = *(const float4*)(wr + o); \
      acc[o+0] = fmaf((xs), w4.x, acc[o+0]); \
      acc[o+1] = fmaf((xs), w4.y, acc[o+1]); \
      acc[o+2] = fmaf((xs), w4.z, acc[o+2]); \
      acc[o+3] = fmaf((xs), w4.w, acc[o+3]); } }
#pragma unroll 2
  for (int q = 0; q < 32; ++q) {
    const float4 hv = hr[q];
    HWSTEP(4*q+0, hv.x); HWSTEP(4*q+1, hv.y); HWSTEP(4*q+2, hv.z); HWSTEP(4*q+3, hv.w);
  }
#undef HWSTEP
  float* dp = hw + node * H_DIM + ob;
#pragma unroll
  for (int o = 0; o < 16; ++o) dp[o] = acc[o];
}

// --------------------------------------------------------------- k_heads ----
__global__ __launch_bounds__(256) void k_heads(const float* __restrict__ hw,
                                               const int* __restrict__ knn,
                                               const float* __restrict__ gb,
                                               const float* __restrict__ gow,
                                               const float* __restrict__ gob,
                                               const float* __restrict__ ow,
                                               const float* __restrict__ obv,
                                               float* __restrict__ out) {
  __shared__ unsigned int wgo[H_DIM][64];  // 32 KB
  __shared__ float hbuf[4][H_DIM];         // 2 KB
  for (int s = threadIdx.x; s < H_DIM * 64; s += 256) {
    const int f = s >> 6, l = s & 63;
    const unsigned short u0 = __half_as_ushort(__float2half(gow[f * H_DIM + l]));
    const unsigned short u1 = __half_as_ushort(__float2half(gow[f * H_DIM + 64 + l]));
    wgo[f][l] = (unsigned int)u0 | ((unsigned int)u1 << 16);
  }
  __syncthreads();
  const int wv = threadIdx.x >> 6, l = threadIdx.x & 63;
  const float gbl = gb[l], gbh = gb[64 + l];
  const float gobl = gob[l], gobh = gob[64 + l];
  for (int it = 0; it < 8; ++it) {
    const int i = blockIdx.x * 32 + wv * 8 + it;
    const int* kr = knn + i * K_NN;
    float s0 = hw[i * H_DIM + l], s1 = hw[i * H_DIM + 64 + l];  // explicit self-loop
#pragma unroll
    for (int m = 0; m < K_NN; ++m) {
      const int j = kr[m];
      s0 += hw[j * H_DIM + l];
      s1 += hw[j * H_DIM + 64 + l];
    }
    // deg == k+1 == 17 for every node by construction -> norm == 1/17
    const float hg0 = s0 * (1.0f / 17.0f) + gbl;
    const float hg1 = s1 * (1.0f / 17.0f) + gbh;
    __syncthreads();
    hbuf[wv][l] = hg0; hbuf[wv][64 + l] = hg1;
    __syncthreads();
    float z0 = gobl, z1 = gobh;
#pragma unroll 4
    for (int f = 0; f < H_DIM; ++f) {
      const float hv = hbuf[wv][f];
      const unsigned int wvv = wgo[f][l];
      const float w0 = __half2float(__ushort_as_half((unsigned short)(wvv & 0xffffu)));
      const float w1 = __half2float(__ushort_as_half((unsigned short)(wvv >> 16)));
      z0 = fmaf(hv, w0, z0);
      z1 = fmaf(hv, w1, z1);
    }
    float mx = fmaxf(z0, z1);
#pragma unroll
    for (int s = 1; s < 64; s <<= 1) mx = fmaxf(mx, __shfl_xor(mx, s, 64));
    const float e0 = __expf(z0 - mx), e1 = __expf(z1 - mx);
    float sm = e0 + e1;
#pragma unroll
    for (int s = 1; s < 64; s <<= 1) sm += __shfl_xor(sm, s, 64);
    const float h20 = e0 / sm, h21 = e1 / sm;
    float zc[O_DIM];
#pragma unroll
    for (int c = 0; c < O_DIM; ++c) {
      float a = h20 * ow[l * O_DIM + c] + h21 * ow[(64 + l) * O_DIM + c];
#pragma unroll
      for (int s = 1; s < 64; s <<= 1) a += __shfl_xor(a, s, 64);
      zc[c] = a + obv[c];
    }
    float m10 = zc[0];
#pragma unroll
    for (int c = 1; c < O_DIM; ++c) m10 = fmaxf(m10, zc[c]);
    float es[O_DIM]; float s10 = 0.f;
#pragma unroll
    for (int c = 0; c < O_DIM; ++c) { es[c] = __expf(zc[c] - m10); s10 += es[c]; }
    const float inv = 1.0f / s10;
    if (l < O_DIM) {
      float v = es[0];
#pragma unroll
      for (int c = 1; c < O_DIM; ++c) if (l == c) v = es[c];
      out[i * O_DIM + l] = v * inv;
    }
  }
}

// ---------------------------------------------------------------------------
extern "C" void kernel_launch(void* const* d_in, const int* in_sizes, int n_in,
                              void* d_out, int out_size, void* d_ws, size_t ws_size,
                              hipStream_t stream) {
  (void)in_sizes; (void)n_in; (void)out_size; (void)ws_size;
  const float* x   = (const float*)d_in[0];
  const float* w1  = (const float*)d_in[2];
  const float* b1  = (const float*)d_in[3];
  const float* w2  = (const float*)d_in[4];
  const float* b2  = (const float*)d_in[5];
  const float* gw  = (const float*)d_in[6];
  const float* gb  = (const float*)d_in[7];
  const float* gow = (const float*)d_in[8];
  const float* gob = (const float*)d_in[9];
  const float* ow  = (const float*)d_in[10];
  const float* obv = (const float*)d_in[11];
  float* out = (float*)d_out;

  char* ws = (char*)d_ws;
  constexpr size_t OFF_SQ   = 0;                                          // 64 KB
  constexpr size_t OFF_SQ64 = OFF_SQ   + (size_t)N_NODES * 4;             // 128 KB
  constexpr size_t OFF_XHL  = OFF_SQ64 + (size_t)N_NODES * 8;             // 4 MB
  constexpr size_t OFF_CMIN = OFF_XHL  + (size_t)N_NODES * 128 * 2;       // 2 MB
  constexpr size_t OFF_TAU  = OFF_CMIN + (size_t)N_NODES * 32 * 4;        // 64 KB
  constexpr size_t OFF_CNT  = OFF_TAU  + (size_t)N_NODES * 4;             // 64 KB
  constexpr size_t OFF_CAND = OFF_CNT  + (size_t)N_NODES * 4;             // 8 MB
  constexpr size_t OFF_KNN  = OFF_CAND + (size_t)N_NODES * 128 * 4;       // 1 MB
  constexpr size_t OFF_Q    = OFF_KNN  + (size_t)N_NODES * K_NN * 4;      // 8 MB
  constexpr size_t OFF_H    = OFF_Q    + (size_t)N_NODES * H_DIM * 4;     // 8 MB
  float*     sq   = (float*)    (ws + OFF_SQ);
  double*    sq64 = (double*)   (ws + OFF_SQ64);
  _Float16*  xhl  = (_Float16*) (ws + OFF_XHL);
  float*     cmin = (float*)    (ws + OFF_CMIN);
  float*     tau  = (float*)    (ws + OFF_TAU);
  unsigned*  cnt  = (unsigned*) (ws + OFF_CNT);
  int*       cand = (int*)      (ws + OFF_CAND);
  int*       knn  = (int*)      (ws + OFF_KNN);
  float*     Q    = (float*)    (ws + OFF_Q);
  float*     h    = (float*)    (ws + OFF_H);
  float*     P    = (float*)    (ws + OFF_CAND);  // P aliases cand (dead after rescore)
  float*     hw   = P;                            // hw aliases P (dead after edgeconv)

  k_prep    <<<N_NODES / 256, 256, 0, stream>>>(x, sq, sq64, xhl);
  k_gemm<1> <<<512,           256, 0, stream>>>(xhl, sq, tau, cmin, cnt, cand);
  k_tau     <<<N_NODES / 256, 256, 0, stream>>>(cmin, tau, cnt);
  k_gemm<2> <<<512,           256, 0, stream>>>(xhl, sq, tau, cmin, cnt, cand);
  k_rescore <<<N_NODES,       128, 0, stream>>>(x, sq64, cand, cnt, knn);
  k_lin1<true>  <<<N_NODES / 32, 256, 0, stream>>>(x, w1, b1, P);
  k_lin1<false> <<<N_NODES / 32, 256, 0, stream>>>(x, w1, b1, Q);
  k_edgeconv<<<N_NODES / 32, 256, 0, stream>>>(P, Q, w2, b2, knn, h);
  k_hw      <<<N_NODES / 32, 256, 0, stream>>>(h, gw, hw);
  k_heads   <<<N_NODES / 32, 256, 0, stream>>>(hw, knn, gb, gow, gob, ow, obv, out);
}

// Round 3
// 593.023 us; speedup vs baseline: 3.3560x; 1.6571x over previous
//
#include <hip/hip_runtime.h>
#include <hip/hip_fp16.h>
#include <cfloat>
#include <cmath>

// GNN_Combo pipeline. Round 3: MFMA-based EdgeConv layer2 + merged lin1.
// N=16384 nodes, F=64 in-features, H=128 hidden, K=16 neighbors, O=10 classes.
//
//  k_prep     : sq (fp32), sq64 (fp64), xhl = f16 hi/lo split of x
//  k_gemm<1>  : MFMA distance keys + per-(row,512-col-chunk) min -> cmins[N][32]
//  k_tau      : tau0[row] = 16th-smallest chunk-min; zero cnt
//  k_gemm<2>  : identical GEMM; append cols with key <= tau0 (E[cnt]~23, cap 128)
//  k_rescore  : fp64 exact rescore -> exact top-16 (knn)
//  k_lin12    : P = x@(W1top-W1bot)+b1 and Q = x@W1bot in one pass
//  k_edgeconv : per node: A=relu(P_i+Q_j) [16x128] -> A@W2 via mfma 16x16x32 f16
//               -> +b2 -> log_softmax rows -> max over 16 -> h[i]
//  k_hw       : hw = h @ gcn_w
//  k_heads    : GCN avg(17)+b; softmax(h@Wgo+b); softmax(.@Wo+b)

#define N_NODES 16384
#define F_IN    64
#define H_DIM   128
#define K_NN    16
#define O_DIM   10

typedef _Float16 half8  __attribute__((ext_vector_type(8)));
typedef _Float16 half4v __attribute__((ext_vector_type(4)));
typedef float    floatx4 __attribute__((ext_vector_type(4)));

// ---------------------------------------------------------------- k_prep ----
__global__ __launch_bounds__(256) void k_prep(const float* __restrict__ x,
                                              float* __restrict__ sq,
                                              double* __restrict__ sq64,
                                              _Float16* __restrict__ xhl) {
  const int i = blockIdx.x * 256 + threadIdx.x;
  if (i >= N_NODES) return;
  const float4* r = (const float4*)(x + i * F_IN);
  float s = 0.f; double sd = 0.0;
#pragma unroll
  for (int q = 0; q < 16; ++q) {
    const float4 v = r[q];
    s += v.x*v.x + v.y*v.y + v.z*v.z + v.w*v.w;
    sd += (double)v.x*v.x + (double)v.y*v.y + (double)v.z*v.z + (double)v.w*v.w;
    half4v hi, lo;
    hi[0] = (_Float16)v.x; hi[1] = (_Float16)v.y;
    hi[2] = (_Float16)v.z; hi[3] = (_Float16)v.w;
    lo[0] = (_Float16)(v.x - (float)hi[0]); lo[1] = (_Float16)(v.y - (float)hi[1]);
    lo[2] = (_Float16)(v.z - (float)hi[2]); lo[3] = (_Float16)(v.w - (float)hi[3]);
    *(half4v*)(xhl + (size_t)i * 128 + 4 * q)      = hi;
    *(half4v*)(xhl + (size_t)i * 128 + 64 + 4 * q) = lo;
  }
  sq[i] = s; sq64[i] = sd;
}

// ---------------------------------------------------------------- k_gemm ----
template<int PHASE>
__global__ __launch_bounds__(256, 2) void k_gemm(const _Float16* __restrict__ xhl,
                                                 const float* __restrict__ sq,
                                                 const float* __restrict__ tau,
                                                 float* __restrict__ cmins,
                                                 unsigned* __restrict__ cnt,
                                                 int* __restrict__ cand) {
  __shared__ __align__(16) _Float16 stage[128 * 136];  // 34816 B
  __shared__ float sqs[128];
  const int tid = threadIdx.x;
  const int wv = tid >> 6, l = tid & 63;
  const int lane16 = l & 15, quad = l >> 4;
  const int rowblk = (blockIdx.x >> 3) * 256;
  const int seg = blockIdx.x & 7;
  const int rw = rowblk + wv * 64;

  half8 A[4][4];  // [rowset][kb: hi0,hi1,lo0,lo1]
#pragma unroll
  for (int s = 0; s < 4; ++s) {
    const _Float16* ap = xhl + (size_t)(rw + s * 16 + lane16) * 128 + quad * 8;
#pragma unroll
    for (int kb = 0; kb < 4; ++kb) A[s][kb] = *(const half8*)(ap + kb * 32);
  }
  float tau_r[16];
  float rmin[16];
  if (PHASE == 2) {
#pragma unroll
    for (int s = 0; s < 4; ++s)
#pragma unroll
      for (int q = 0; q < 4; ++q)
        tau_r[s * 4 + q] = tau[rw + s * 16 + quad * 4 + q];
  } else {
#pragma unroll
    for (int t = 0; t < 16; ++t) rmin[t] = FLT_MAX;
  }

  for (int tile = 0; tile < 16; ++tile) {
    const int c0 = seg * 2048 + tile * 128;
    __syncthreads();
    {
      const int col = tid >> 1, part = tid & 1;
      const _Float16* g = xhl + (size_t)(c0 + col) * 128 + part * 64;
      _Float16* d = stage + col * 136 + part * 64;
#pragma unroll
      for (int j = 0; j < 8; ++j)
        *(half8*)(d + j * 8) = *(const half8*)(g + j * 8);
      if (tid < 128) sqs[tid] = sq[c0 + tid];
    }
    __syncthreads();
#pragma unroll 1
    for (int st = 0; st < 8; ++st) {
      const _Float16* bp = stage + (st * 16 + lane16) * 136 + quad * 8;
      const half8 B0 = *(const half8*)(bp);        // hi feats 0-31
      const half8 B1 = *(const half8*)(bp + 32);   // hi feats 32-63
      const half8 B2 = *(const half8*)(bp + 64);   // lo feats 0-31
      const half8 B3 = *(const half8*)(bp + 96);   // lo feats 32-63
      const float sqv = sqs[st * 16 + lane16];
      floatx4 acc[4];
#pragma unroll
      for (int s = 0; s < 4; ++s) acc[s] = (floatx4)0.f;
#define MF(s, ab, bb) acc[s] = __builtin_amdgcn_mfma_f32_16x16x32_f16(A[s][ab], bb, acc[s], 0, 0, 0)
#pragma unroll
      for (int s = 0; s < 4; ++s) MF(s, 0, B0);   // hi*hi
#pragma unroll
      for (int s = 0; s < 4; ++s) MF(s, 1, B1);
#pragma unroll
      for (int s = 0; s < 4; ++s) MF(s, 2, B0);   // lo*hi
#pragma unroll
      for (int s = 0; s < 4; ++s) MF(s, 3, B1);
#pragma unroll
      for (int s = 0; s < 4; ++s) MF(s, 0, B2);   // hi*lo
#pragma unroll
      for (int s = 0; s < 4; ++s) MF(s, 1, B3);
#undef MF
      if (PHASE == 1) {
#pragma unroll
        for (int s = 0; s < 4; ++s)
#pragma unroll
          for (int q = 0; q < 4; ++q)
            rmin[s * 4 + q] = fminf(rmin[s * 4 + q], fmaf(-2.f, acc[s][q], sqv));
      } else {
        const int colb = c0 + st * 16 + lane16;
#pragma unroll
        for (int s = 0; s < 4; ++s) {
          const float k0 = fmaf(-2.f, acc[s][0], sqv);
          const float k1 = fmaf(-2.f, acc[s][1], sqv);
          const float k2 = fmaf(-2.f, acc[s][2], sqv);
          const float k3 = fmaf(-2.f, acc[s][3], sqv);
          const float d01 = fminf(k0 - tau_r[s * 4 + 0], k1 - tau_r[s * 4 + 1]);
          const float d23 = fminf(k2 - tau_r[s * 4 + 2], k3 - tau_r[s * 4 + 3]);
          if (__ballot(fminf(d01, d23) <= 0.f)) {
            const int rbase = rw + s * 16 + quad * 4;
            if (k0 <= tau_r[s * 4 + 0]) {
              const unsigned pos = atomicAdd(&cnt[rbase + 0], 1u);
              if (pos < 128u) cand[(size_t)(rbase + 0) * 128 + pos] = colb;
            }
            if (k1 <= tau_r[s * 4 + 1]) {
              const unsigned pos = atomicAdd(&cnt[rbase + 1], 1u);
              if (pos < 128u) cand[(size_t)(rbase + 1) * 128 + pos] = colb;
            }
            if (k2 <= tau_r[s * 4 + 2]) {
              const unsigned pos = atomicAdd(&cnt[rbase + 2], 1u);
              if (pos < 128u) cand[(size_t)(rbase + 2) * 128 + pos] = colb;
            }
            if (k3 <= tau_r[s * 4 + 3]) {
              const unsigned pos = atomicAdd(&cnt[rbase + 3], 1u);
              if (pos < 128u) cand[(size_t)(rbase + 3) * 128 + pos] = colb;
            }
          }
        }
      }
    }
    if (PHASE == 1 && (tile & 3) == 3) {   // chunk boundary (512 cols)
#pragma unroll
      for (int t = 0; t < 16; ++t) {
#pragma unroll
        for (int d = 1; d < 16; d <<= 1)
          rmin[t] = fminf(rmin[t], __shfl_xor(rmin[t], d, 64));
      }
      const int chunk = seg * 4 + (tile >> 2);
      float v = rmin[0];
#pragma unroll
      for (int t = 1; t < 16; ++t) if (lane16 == t) v = rmin[t];
      const int row = rw + (lane16 >> 2) * 16 + quad * 4 + (lane16 & 3);
      cmins[(size_t)row * 32 + chunk] = v;
#pragma unroll
      for (int t = 0; t < 16; ++t) rmin[t] = FLT_MAX;
    }
  }
}

// ----------------------------------------------------------------- k_tau ----
__global__ __launch_bounds__(256) void k_tau(const float* __restrict__ cmins,
                                             float* __restrict__ tau,
                                             unsigned* __restrict__ cnt) {
  const int r = blockIdx.x * 256 + threadIdx.x;
  if (r >= N_NODES) return;
  float v[32];
#pragma unroll
  for (int j = 0; j < 32; ++j) v[j] = cmins[(size_t)r * 32 + j];
  float t16 = FLT_MAX;
#pragma unroll 1
  for (int j = 0; j < 32; ++j) {
    int rk = 0;
#pragma unroll
    for (int m = 0; m < 32; ++m)
      rk += (v[m] < v[j]) || (v[m] == v[j] && m < j);
    if (rk == 15) t16 = v[j];
  }
  tau[r] = t16;
  cnt[r] = 0;
}

// ------------------------------------------------------------- k_rescore ----
__global__ __launch_bounds__(128) void k_rescore(const float* __restrict__ x,
                                                 const double* __restrict__ sq64,
                                                 const int* __restrict__ cand,
                                                 const unsigned* __restrict__ cnt,
                                                 int* __restrict__ knn) {
  __shared__ float  xi[F_IN];
  __shared__ double keys[128];
  __shared__ int    ids[128];
  const int i = blockIdx.x, t = threadIdx.x;
  const unsigned c = cnt[i];
  const int n = (int)(c < 128u ? c : 128u);
  if (t < F_IN) xi[t] = x[i * F_IN + t];
  __syncthreads();
  double key = 1e300; int id = 0x7fffffff;
  if (t < n) {
    id = cand[(size_t)i * 128 + t];
    const float4* xc4 = (const float4*)(x + (size_t)id * F_IN);
    double d0 = 0.0, d1 = 0.0, d2 = 0.0, d3 = 0.0;
#pragma unroll
    for (int q = 0; q < 16; ++q) {
      const float4 v = xc4[q];
      d0 += (double)xi[4*q+0] * (double)v.x;
      d1 += (double)xi[4*q+1] * (double)v.y;
      d2 += (double)xi[4*q+2] * (double)v.z;
      d3 += (double)xi[4*q+3] * (double)v.w;
    }
    key = sq64[id] - 2.0 * ((d0 + d1) + (d2 + d3));
  }
  keys[t] = key; ids[t] = id;
  __syncthreads();
  int rank = 0;
#pragma unroll 4
  for (int cix = 0; cix < 128; ++cix) {
    const double kc = keys[cix]; const int ic = ids[cix];
    rank += (kc < key) || (kc == key && ic < id);
  }
  if (t < n && rank < K_NN) knn[i * K_NN + rank] = id;
}

// --------------------------------------------------------------- k_lin12 ----
// One pass: R = x@W1top, Qa = x@W1bot; P = R - Qa + b1; Q = Qa.
__global__ __launch_bounds__(256, 2) void k_lin12(const float* __restrict__ x,
                                                  const float* __restrict__ w1,
                                                  const float* __restrict__ b1,
                                                  float* __restrict__ P,
                                                  float* __restrict__ Q) {
  __shared__ float wl[2 * F_IN][H_DIM];   // 64 KB
  for (int s = threadIdx.x; s < 2 * F_IN * H_DIM; s += 256) wl[s >> 7][s & 127] = w1[s];
  __syncthreads();
  const int node = blockIdx.x * 32 + (threadIdx.x & 31);
  const int ob = (threadIdx.x >> 5) * 16;   // 8 groups x 16 outs
  float accR[16], accQ[16];
#pragma unroll
  for (int o = 0; o < 16; ++o) { accR[o] = 0.f; accQ[o] = 0.f; }
  const float4* xr = (const float4*)(x + node * F_IN);
#define L1STEP(ff, xs) { \
    const float* wt_ = &wl[(ff)][ob]; \
    const float* wb_ = &wl[(ff) + F_IN][ob]; \
    _Pragma("unroll") \
    for (int o = 0; o < 16; o += 4) { \
      const float4 t4 = *(const float4*)(wt_ + o); \
      const float4 b4 = *(const float4*)(wb_ + o); \
      accR[o+0] = fmaf((xs), t4.x, accR[o+0]); accQ[o+0] = fmaf((xs), b4.x, accQ[o+0]); \
      accR[o+1] = fmaf((xs), t4.y, accR[o+1]); accQ[o+1] = fmaf((xs), b4.y, accQ[o+1]); \
      accR[o+2] = fmaf((xs), t4.z, accR[o+2]); accQ[o+2] = fmaf((xs), b4.z, accQ[o+2]); \
      accR[o+3] = fmaf((xs), t4.w, accR[o+3]); accQ[o+3] = fmaf((xs), b4.w, accQ[o+3]); } }
#pragma unroll 2
  for (int q = 0; q < 16; ++q) {
    const float4 xv = xr[q];
    L1STEP(4*q+0, xv.x); L1STEP(4*q+1, xv.y); L1STEP(4*q+2, xv.z); L1STEP(4*q+3, xv.w);
  }
#undef L1STEP
  float* pp = P + node * H_DIM + ob;
  float* qp = Q + node * H_DIM + ob;
#pragma unroll
  for (int o = 0; o < 16; ++o) {
    pp[o] = accR[o] - accQ[o] + b1[ob + o];
    qp[o] = accQ[o];
  }
}

// ------------------------------------------------------------ k_edgeconv ----
// Wave-per-node (8 nodes/wave, 32/block). W2^T staged once per block as f16
// wt[n][k] (pad 136 -> uniform 8-phase b128 reads). Per node: 64 lanes gather
// Q_j rows + P_i, build A=relu(P+Q) in f16 directly in A-fragment order in
// per-wave LDS (no block barrier needed), run 8 N-tiles x 4 K-blocks of
// mfma_f32_16x16x32_f16, add b2, log_softmax per row (shfl within 16-lane
// groups), max over the 16 rows, store h[i].
__global__ __launch_bounds__(256, 2) void k_edgeconv(const float* __restrict__ P,
                                                     const float* __restrict__ Q,
                                                     const float* __restrict__ w2,
                                                     const float* __restrict__ b2,
                                                     const int* __restrict__ knn,
                                                     float* __restrict__ h) {
  __shared__ __align__(16) _Float16 wt[H_DIM * 136];   // 34816 B, wt[n*136+k]
  __shared__ __align__(16) _Float16 afr[4][2048];      // 16384 B, per-wave A frags
  const int tid = threadIdx.x;
  const int wv = tid >> 6, l = tid & 63;
  const int lane16 = l & 15, quad = l >> 4;

  {  // stage W2^T as f16 (one-time; w2 is L2-hot across blocks)
    const int n = tid >> 1, k0 = (tid & 1) * 64;
    const float* wsrc = w2 + n;
    _Float16* wdst = wt + n * 136 + k0;
#pragma unroll
    for (int c = 0; c < 8; ++c) {
      half8 hv;
#pragma unroll
      for (int u = 0; u < 8; ++u)
        hv[u] = (_Float16)wsrc[(size_t)(k0 + c * 8 + u) * H_DIM];
      *(half8*)(wdst + c * 8) = hv;
    }
  }
  __syncthreads();

  float b2r[8];
#pragma unroll
  for (int tile = 0; tile < 8; ++tile) b2r[tile] = b2[tile * 16 + lane16];

  _Float16* aw = afr[wv];
  for (int it = 0; it < 8; ++it) {
    const int i = blockIdx.x * 32 + wv * 8 + it;
    // ---- build A = relu(P_i + Q_j) in fragment order ----
    {
      const int m = lane16, kq = quad;          // lane: message m, k-chunk kq*32
      const int j = knn[i * K_NN + m];
      const float4* pq = (const float4*)(P + (size_t)i * H_DIM + kq * 32);
      const float4* qq = (const float4*)(Q + (size_t)j * H_DIM + kq * 32);
#pragma unroll
      for (int c = 0; c < 4; ++c) {
        const float4 pa = pq[2 * c],     qa = qq[2 * c];
        const float4 pb = pq[2 * c + 1], qb = qq[2 * c + 1];
        half8 hv;
        hv[0] = (_Float16)fmaxf(pa.x + qa.x, 0.f);
        hv[1] = (_Float16)fmaxf(pa.y + qa.y, 0.f);
        hv[2] = (_Float16)fmaxf(pa.z + qa.z, 0.f);
        hv[3] = (_Float16)fmaxf(pa.w + qa.w, 0.f);
        hv[4] = (_Float16)fmaxf(pb.x + qb.x, 0.f);
        hv[5] = (_Float16)fmaxf(pb.y + qb.y, 0.f);
        hv[6] = (_Float16)fmaxf(pb.z + qb.z, 0.f);
        hv[7] = (_Float16)fmaxf(pb.w + qb.w, 0.f);
        *(half8*)(aw + kq * 512 + c * 128 + m * 8) = hv;
      }
    }
    // ---- A-fragment loads (wave-internal LDS dep; lgkmcnt handled) ----
    half8 A[4];
#pragma unroll
    for (int kb = 0; kb < 4; ++kb) A[kb] = *(const half8*)(aw + kb * 512 + l * 8);
    // ---- 8 N-tiles x 4 K-blocks MFMA ----
    floatx4 acc[8];
#pragma unroll
    for (int tile = 0; tile < 8; ++tile) acc[tile] = (floatx4)0.f;
#pragma unroll
    for (int kb = 0; kb < 4; ++kb) {
#pragma unroll
      for (int tile = 0; tile < 8; ++tile) {
        const half8 B = *(const half8*)(wt + (tile * 16 + lane16) * 136 + kb * 32 + quad * 8);
        acc[tile] = __builtin_amdgcn_mfma_f32_16x16x32_f16(A[kb], B, acc[tile], 0, 0, 0);
      }
    }
    // ---- epilogue: +b2, per-row log_softmax, max over 16 rows ----
    // z[row = quad*4+r][col = tile*16+lane16] = acc[tile][r] + b2r[tile]
    float lse[4];
#pragma unroll
    for (int r = 0; r < 4; ++r) {
      float mx = acc[0][r] + b2r[0];
#pragma unroll
      for (int tile = 1; tile < 8; ++tile) mx = fmaxf(mx, acc[tile][r] + b2r[tile]);
      mx = fmaxf(mx, __shfl_xor(mx, 1, 64));
      mx = fmaxf(mx, __shfl_xor(mx, 2, 64));
      mx = fmaxf(mx, __shfl_xor(mx, 4, 64));
      mx = fmaxf(mx, __shfl_xor(mx, 8, 64));
      float e = 0.f;
#pragma unroll
      for (int tile = 0; tile < 8; ++tile) e += __expf(acc[tile][r] + b2r[tile] - mx);
      e += __shfl_xor(e, 1, 64);
      e += __shfl_xor(e, 2, 64);
      e += __shfl_xor(e, 4, 64);
      e += __shfl_xor(e, 8, 64);
      lse[r] = mx + __logf(e);
    }
#pragma unroll
    for (int tile = 0; tile < 8; ++tile) {
      float v = acc[tile][0] + b2r[tile] - lse[0];
#pragma unroll
      for (int r = 1; r < 4; ++r) v = fmaxf(v, acc[tile][r] + b2r[tile] - lse[r]);
      v = fmaxf(v, __shfl_xor(v, 16, 64));
      v = fmaxf(v, __shfl_xor(v, 32, 64));
      if (quad == 0) h[(size_t)i * H_DIM + tile * 16 + lane16] = v;
    }
  }
}

// ----------------------------------------------------------------- k_hw -----
__global__ __launch_bounds__(256) void k_hw(const float* __restrict__ h,
                                            const float* __restrict__ gw,
                                            float* __restrict__ hw) {
  __shared__ float wl[H_DIM][H_DIM];   // 64 KB
  for (int s = threadIdx.x; s < H_DIM * H_DIM; s += 256) wl[s >> 7][s & 127] = gw[s];
  __syncthreads();
  const int node = blockIdx.x * 32 + (threadIdx.x & 31);
  const int ob = (threadIdx.x >> 5) * 16;
  float acc[16];
#pragma unroll
  for (int o = 0; o < 16; ++o) acc[o] = 0.f;
  const float4* hr = (const float4*)(h + node * H_DIM);
#define HWSTEP(ff, xs) { \
    const float* wr = &wl[(ff)][ob]; \
    _Pragma("unroll") \
    for (int o = 0; o < 16; o += 4) { const float4 w4 = *(const float4*)(wr + o); \
      acc[o+0] = fmaf((xs), w4.x, acc[o+0]); \
      acc[o+1] = fmaf((xs), w4.y, acc[o+1]); \
      acc[o+2] = fmaf((xs), w4.z, acc[o+2]); \
      acc[o+3] = fmaf((xs), w4.w, acc[o+3]); } }
#pragma unroll 2
  for (int q = 0; q < 32; ++q) {
    const float4 hv = hr[q];
    HWSTEP(4*q+0, hv.x); HWSTEP(4*q+1, hv.y); HWSTEP(4*q+2, hv.z); HWSTEP(4*q+3, hv.w);
  }
#undef HWSTEP
  float* dp = hw + node * H_DIM + ob;
#pragma unroll
  for (int o = 0; o < 16; ++o) dp[o] = acc[o];
}

// --------------------------------------------------------------- k_heads ----
__global__ __launch_bounds__(256) void k_heads(const float* __restrict__ hw,
                                               const int* __restrict__ knn,
                                               const float* __restrict__ gb,
                                               const float* __restrict__ gow,
                                               const float* __restrict__ gob,
                                               const float* __restrict__ ow,
                                               const float* __restrict__ obv,
                                               float* __restrict__ out) {
  __shared__ unsigned int wgo[H_DIM][64];  // 32 KB
  __shared__ float hbuf[4][H_DIM];         // 2 KB
  for (int s = threadIdx.x; s < H_DIM * 64; s += 256) {
    const int f = s >> 6, l = s & 63;
    const unsigned short u0 = __half_as_ushort(__float2half(gow[f * H_DIM + l]));
    const unsigned short u1 = __half_as_ushort(__float2half(gow[f * H_DIM + 64 + l]));
    wgo[f][l] = (unsigned int)u0 | ((unsigned int)u1 << 16);
  }
  __syncthreads();
  const int wv = threadIdx.x >> 6, l = threadIdx.x & 63;
  const float gbl = gb[l], gbh = gb[64 + l];
  const float gobl = gob[l], gobh = gob[64 + l];
  for (int it = 0; it < 8; ++it) {
    const int i = blockIdx.x * 32 + wv * 8 + it;
    const int* kr = knn + i * K_NN;
    float s0 = hw[i * H_DIM + l], s1 = hw[i * H_DIM + 64 + l];  // explicit self-loop
#pragma unroll
    for (int m = 0; m < K_NN; ++m) {
      const int j = kr[m];
      s0 += hw[j * H_DIM + l];
      s1 += hw[j * H_DIM + 64 + l];
    }
    // deg == k+1 == 17 for every node by construction -> norm == 1/17
    const float hg0 = s0 * (1.0f / 17.0f) + gbl;
    const float hg1 = s1 * (1.0f / 17.0f) + gbh;
    __syncthreads();
    hbuf[wv][l] = hg0; hbuf[wv][64 + l] = hg1;
    __syncthreads();
    float z0 = gobl, z1 = gobh;
#pragma unroll 4
    for (int f = 0; f < H_DIM; ++f) {
      const float hv = hbuf[wv][f];
      const unsigned int wvv = wgo[f][l];
      const float w0 = __half2float(__ushort_as_half((unsigned short)(wvv & 0xffffu)));
      const float w1 = __half2float(__ushort_as_half((unsigned short)(wvv >> 16)));
      z0 = fmaf(hv, w0, z0);
      z1 = fmaf(hv, w1, z1);
    }
    float mx = fmaxf(z0, z1);
#pragma unroll
    for (int s = 1; s < 64; s <<= 1) mx = fmaxf(mx, __shfl_xor(mx, s, 64));
    const float e0 = __expf(z0 - mx), e1 = __expf(z1 - mx);
    float sm = e0 + e1;
#pragma unroll
    for (int s = 1; s < 64; s <<= 1) sm += __shfl_xor(sm, s, 64);
    const float h20 = e0 / sm, h21 = e1 / sm;
    float zc[O_DIM];
#pragma unroll
    for (int c = 0; c < O_DIM; ++c) {
      float a = h20 * ow[l * O_DIM + c] + h21 * ow[(64 + l) * O_DIM + c];
#pragma unroll
      for (int s = 1; s < 64; s <<= 1) a += __shfl_xor(a, s, 64);
      zc[c] = a + obv[c];
    }
    float m10 = zc[0];
#pragma unroll
    for (int c = 1; c < O_DIM; ++c) m10 = fmaxf(m10, zc[c]);
    float es[O_DIM]; float s10 = 0.f;
#pragma unroll
    for (int c = 0; c < O_DIM; ++c) { es[c] = __expf(zc[c] - m10); s10 += es[c]; }
    const float inv = 1.0f / s10;
    if (l < O_DIM) {
      float v = es[0];
#pragma unroll
      for (int c = 1; c < O_DIM; ++c) if (l == c) v = es[c];
      out[i * O_DIM + l] = v * inv;
    }
  }
}

// ---------------------------------------------------------------------------
extern "C" void kernel_launch(void* const* d_in, const int* in_sizes, int n_in,
                              void* d_out, int out_size, void* d_ws, size_t ws_size,
                              hipStream_t stream) {
  (void)in_sizes; (void)n_in; (void)out_size; (void)ws_size;
  const float* x   = (const float*)d_in[0];
  const float* w1  = (const float*)d_in[2];
  const float* b1  = (const float*)d_in[3];
  const float* w2  = (const float*)d_in[4];
  const float* b2  = (const float*)d_in[5];
  const float* gw  = (const float*)d_in[6];
  const float* gb  = (const float*)d_in[7];
  const float* gow = (const float*)d_in[8];
  const float* gob = (const float*)d_in[9];
  const float* ow  = (const float*)d_in[10];
  const float* obv = (const float*)d_in[11];
  float* out = (float*)d_out;

  char* ws = (char*)d_ws;
  constexpr size_t OFF_SQ   = 0;                                          // 64 KB
  constexpr size_t OFF_SQ64 = OFF_SQ   + (size_t)N_NODES * 4;             // 128 KB
  constexpr size_t OFF_XHL  = OFF_SQ64 + (size_t)N_NODES * 8;             // 4 MB
  constexpr size_t OFF_CMIN = OFF_XHL  + (size_t)N_NODES * 128 * 2;       // 2 MB
  constexpr size_t OFF_TAU  = OFF_CMIN + (size_t)N_NODES * 32 * 4;        // 64 KB
  constexpr size_t OFF_CNT  = OFF_TAU  + (size_t)N_NODES * 4;             // 64 KB
  constexpr size_t OFF_CAND = OFF_CNT  + (size_t)N_NODES * 4;             // 8 MB
  constexpr size_t OFF_KNN  = OFF_CAND + (size_t)N_NODES * 128 * 4;       // 1 MB
  constexpr size_t OFF_Q    = OFF_KNN  + (size_t)N_NODES * K_NN * 4;      // 8 MB
  constexpr size_t OFF_H    = OFF_Q    + (size_t)N_NODES * H_DIM * 4;     // 8 MB
  float*     sq   = (float*)    (ws + OFF_SQ);
  double*    sq64 = (double*)   (ws + OFF_SQ64);
  _Float16*  xhl  = (_Float16*) (ws + OFF_XHL);
  float*     cmin = (float*)    (ws + OFF_CMIN);
  float*     tau  = (float*)    (ws + OFF_TAU);
  unsigned*  cnt  = (unsigned*) (ws + OFF_CNT);
  int*       cand = (int*)      (ws + OFF_CAND);
  int*       knn  = (int*)      (ws + OFF_KNN);
  float*     Q    = (float*)    (ws + OFF_Q);
  float*     h    = (float*)    (ws + OFF_H);
  float*     P    = (float*)    (ws + OFF_CAND);  // P aliases cand (dead after rescore)
  float*     hw   = P;                            // hw aliases P (dead after edgeconv)

  k_prep    <<<N_NODES / 256, 256, 0, stream>>>(x, sq, sq64, xhl);
  k_gemm<1> <<<512,           256, 0, stream>>>(xhl, sq, tau, cmin, cnt, cand);
  k_tau     <<<N_NODES / 256, 256, 0, stream>>>(cmin, tau, cnt);
  k_gemm<2> <<<512,           256, 0, stream>>>(xhl, sq, tau, cmin, cnt, cand);
  k_rescore <<<N_NODES,       128, 0, stream>>>(x, sq64, cand, cnt, knn);
  k_lin12   <<<N_NODES / 32,  256, 0, stream>>>(x, w1, b1, P, Q);
  k_edgeconv<<<N_NODES / 32,  256, 0, stream>>>(P, Q, w2, b2, knn, h);
  k_hw      <<<N_NODES / 32,  256, 0, stream>>>(h, gw, hw);
  k_heads   <<<N_NODES / 32,  256, 0, stream>>>(hw, knn, gb, gow, gob, ow, obv, out);
}